// Round 1
// baseline (162.837 us; speedup 1.0000x reference)
//
#include <hip/hip_runtime.h>

// Problem constants (from reference)
#define T_TOKENS 4096      // B*C = 4*1024
#define D_DIM    2048
#define NEXP     8
#define CAP      1280      // floor(2 * 1.25 * 4096 / 8), already even

// ---------------------------------------------------------------------------
// Kernel 1: gating. One wave (64 lanes) per token.
// Computes 16 dot products (8 w_g + 8 w_noise) of length 2048, then lane 0
// applies softplus*noise, picks top-2 (JAX tie-break: lowest index first),
// computes the 2-way softmax probs, writes idx/prob in slot-major order.
// ---------------------------------------------------------------------------
__global__ void gating_kernel(const float* __restrict__ x,
                              const float* __restrict__ noise,
                              const float* __restrict__ w_g,
                              const float* __restrict__ w_noise,
                              int*   __restrict__ top_idx,    // [2*T] slot-major
                              float* __restrict__ top_prob)   // [2*T] slot-major
{
    const int wave = threadIdx.x >> 6;
    const int lane = threadIdx.x & 63;
    const int t = blockIdx.x * 4 + wave;
    if (t >= T_TOKENS) return;

    const float4* xv = reinterpret_cast<const float4*>(x + (size_t)t * D_DIM);

    float acc[16];
#pragma unroll
    for (int j = 0; j < 16; ++j) acc[j] = 0.f;

    // D/4 = 512 float4 per row; 64 lanes -> 8 iterations
#pragma unroll
    for (int it = 0; it < 8; ++it) {
        const int c = it * 64 + lane;   // float4 column index
        const float4 xval = xv[c];
#pragma unroll
        for (int e = 0; e < NEXP; ++e) {
            const float4 g = reinterpret_cast<const float4*>(w_g + (size_t)e * D_DIM)[c];
            acc[e] += xval.x * g.x + xval.y * g.y + xval.z * g.z + xval.w * g.w;
            const float4 n = reinterpret_cast<const float4*>(w_noise + (size_t)e * D_DIM)[c];
            acc[8 + e] += xval.x * n.x + xval.y * n.y + xval.z * n.z + xval.w * n.w;
        }
    }

    // wave-wide reduction of the 16 accumulators
#pragma unroll
    for (int j = 0; j < 16; ++j) {
        float v = acc[j];
#pragma unroll
        for (int off = 32; off > 0; off >>= 1) v += __shfl_down(v, off, 64);
        acc[j] = v;   // valid on lane 0
    }

    if (lane == 0) {
        float logit[NEXP];
#pragma unroll
        for (int e = 0; e < NEXP; ++e) {
            const float z = acc[8 + e];
            // stable softplus: max(z,0) + log1p(exp(-|z|))
            const float sp = fmaxf(z, 0.f) + log1pf(expf(-fabsf(z)));
            logit[e] = acc[e] + sp * noise[(size_t)t * NEXP + e];
        }
        // top-1 (strict > keeps first occurrence on ties, matches jax top_k)
        int i0 = 0; float v0 = logit[0];
#pragma unroll
        for (int e = 1; e < NEXP; ++e) {
            if (logit[e] > v0) { v0 = logit[e]; i0 = e; }
        }
        // top-2 (first occurrence among the rest)
        int i1 = -1; float v1 = -3.402823466e38f;
#pragma unroll
        for (int e = 0; e < NEXP; ++e) {
            if (e != i0 && logit[e] > v1) { v1 = logit[e]; i1 = e; }
        }
        // softmax over the two kept logits (others are -inf -> 0)
        const float e1  = expf(v1 - v0);
        const float inv = 1.f / (1.f + e1);
        top_idx[t]            = i0;
        top_idx[T_TOKENS + t] = i1;
        top_prob[t]            = inv;        // prob of slot-0 expert
        top_prob[T_TOKENS + t] = e1 * inv;   // prob of slot-1 expert
    }
}

// ---------------------------------------------------------------------------
// Kernel 2: per-expert prefix scan over the 8192 slot-major entries.
// One wave per expert (8 waves, 1 block). Ballot-based 64-wide scan,
// 128 chunks. rank[i] = position-in-expert, or -1 if >= capacity.
// Each entry is written by exactly the wave owning its expert.
// ---------------------------------------------------------------------------
__global__ void scan_kernel(const int* __restrict__ top_idx,
                            int* __restrict__ rank)          // [2*T]
{
    const int e    = threadIdx.x >> 6;   // expert = wave id
    const int lane = threadIdx.x & 63;

    int base = 0;
    for (int chunk = 0; chunk < (2 * T_TOKENS) / 64; ++chunk) {
        const int i = chunk * 64 + lane;
        const bool match = (top_idx[i] == e);
        const unsigned long long m = __ballot(match);
        if (match) {
            const int r = base + __popcll(m & ((1ull << lane) - 1ull));
            rank[i] = (r < CAP) ? r : -1;
        }
        base += __popcll(m);
    }
}

// ---------------------------------------------------------------------------
// Kernel 3: scatter. One block per (slot, token) assignment (8192 blocks).
// Writes the two sparse scalars and copies x[t] into expert_batches row.
// d_out has been zeroed by hipMemsetAsync beforehand.
// ---------------------------------------------------------------------------
__global__ void scatter_kernel(const float* __restrict__ x,
                               const int*   __restrict__ top_idx,
                               const float* __restrict__ top_prob,
                               const int*   __restrict__ rank,
                               float* __restrict__ exp_weights,    // [T,8,CAP]
                               float* __restrict__ exp_mask,       // [T,8,CAP]
                               float* __restrict__ expert_batches) // [8,CAP,D]
{
    const int i = blockIdx.x;            // slot-major entry: i = s*T + t
    const int r = rank[i];
    if (r < 0) return;
    const int t = i & (T_TOKENS - 1);
    const int e = top_idx[i];

    if (threadIdx.x == 0) {
        const size_t off = ((size_t)t * NEXP + e) * CAP + r;
        exp_weights[off] = top_prob[i];
        exp_mask[off]    = 1.0f;
    }

    const float4* src = reinterpret_cast<const float4*>(x + (size_t)t * D_DIM);
    float4*       dst = reinterpret_cast<float4*>(expert_batches + ((size_t)e * CAP + r) * D_DIM);
#pragma unroll
    for (int c = threadIdx.x; c < D_DIM / 4; c += 256) dst[c] = src[c];
}

// ---------------------------------------------------------------------------
extern "C" void kernel_launch(void* const* d_in, const int* in_sizes, int n_in,
                              void* d_out, int out_size, void* d_ws, size_t ws_size,
                              hipStream_t stream)
{
    const float* x       = (const float*)d_in[0];
    const float* noise   = (const float*)d_in[1];
    const float* w_g     = (const float*)d_in[2];
    const float* w_noise = (const float*)d_in[3];

    float* out = (float*)d_out;
    const size_t n_ew = (size_t)T_TOKENS * NEXP * CAP;   // 41,943,040
    float* exp_weights    = out;
    float* exp_mask       = out + n_ew;
    float* expert_batches = out + 2 * n_ew;

    int*   top_idx  = (int*)d_ws;
    float* top_prob = (float*)((char*)d_ws + 2 * T_TOKENS * sizeof(int));
    int*   rank     = (int*)((char*)d_ws + 4 * T_TOKENS * sizeof(int));

    // zero the entire output (419 MB) — the sparse scatters land on top
    hipMemsetAsync(d_out, 0, (size_t)out_size * sizeof(float), stream);

    gating_kernel<<<T_TOKENS / 4, 256, 0, stream>>>(x, noise, w_g, w_noise,
                                                    top_idx, top_prob);
    scan_kernel<<<1, 512, 0, stream>>>(top_idx, rank);
    scatter_kernel<<<2 * T_TOKENS, 256, 0, stream>>>(x, top_idx, top_prob, rank,
                                                     exp_weights, exp_mask,
                                                     expert_batches);
}

// Round 3
// 141.193 us; speedup vs baseline: 1.1533x; 1.1533x over previous
//
#include <hip/hip_runtime.h>

// Problem constants (from reference)
#define T_TOKENS 4096      // B*C = 4*1024
#define D_DIM    2048
#define NEXP     8
#define CAP      1280      // floor(2 * 1.25 * 4096 / 8), already even
#define NSLOTS   (NEXP * CAP)   // 10240

// native 16-byte vector type (works with __builtin_nontemporal_store)
typedef float f32x4 __attribute__((ext_vector_type(4)));

// ---------------------------------------------------------------------------
// Kernel 1: gating. One wave (64 lanes) per token.
// Computes 16 dot products (8 w_g + 8 w_noise) of length 2048, then lane 0
// applies softplus*noise, picks top-2 (JAX tie-break: lowest index first),
// computes the 2-way softmax probs, writes idx/prob in slot-major order.
// ---------------------------------------------------------------------------
__global__ void gating_kernel(const float* __restrict__ x,
                              const float* __restrict__ noise,
                              const float* __restrict__ w_g,
                              const float* __restrict__ w_noise,
                              int*   __restrict__ top_idx,    // [2*T] slot-major
                              float* __restrict__ top_prob)   // [2*T] slot-major
{
    const int wave = threadIdx.x >> 6;
    const int lane = threadIdx.x & 63;
    const int t = blockIdx.x * 4 + wave;
    if (t >= T_TOKENS) return;

    const f32x4* xv = reinterpret_cast<const f32x4*>(x + (size_t)t * D_DIM);

    float acc[16];
#pragma unroll
    for (int j = 0; j < 16; ++j) acc[j] = 0.f;

    // D/4 = 512 float4 per row; 64 lanes -> 8 iterations
#pragma unroll
    for (int it = 0; it < 8; ++it) {
        const int c = it * 64 + lane;   // float4 column index
        const f32x4 xval = xv[c];
#pragma unroll
        for (int e = 0; e < NEXP; ++e) {
            const f32x4 g = reinterpret_cast<const f32x4*>(w_g + (size_t)e * D_DIM)[c];
            acc[e] += xval.x * g.x + xval.y * g.y + xval.z * g.z + xval.w * g.w;
            const f32x4 n = reinterpret_cast<const f32x4*>(w_noise + (size_t)e * D_DIM)[c];
            acc[8 + e] += xval.x * n.x + xval.y * n.y + xval.z * n.z + xval.w * n.w;
        }
    }

    // wave-wide reduction of the 16 accumulators
#pragma unroll
    for (int j = 0; j < 16; ++j) {
        float v = acc[j];
#pragma unroll
        for (int off = 32; off > 0; off >>= 1) v += __shfl_down(v, off, 64);
        acc[j] = v;   // valid on lane 0
    }

    if (lane == 0) {
        float logit[NEXP];
#pragma unroll
        for (int e = 0; e < NEXP; ++e) {
            const float z = acc[8 + e];
            // stable softplus: max(z,0) + log1p(exp(-|z|))
            const float sp = fmaxf(z, 0.f) + log1pf(expf(-fabsf(z)));
            logit[e] = acc[e] + sp * noise[(size_t)t * NEXP + e];
        }
        // top-1 (strict > keeps first occurrence on ties, matches jax top_k)
        int i0 = 0; float v0 = logit[0];
#pragma unroll
        for (int e = 1; e < NEXP; ++e) {
            if (logit[e] > v0) { v0 = logit[e]; i0 = e; }
        }
        // top-2 (first occurrence among the rest)
        int i1 = -1; float v1 = -3.402823466e38f;
#pragma unroll
        for (int e = 0; e < NEXP; ++e) {
            if (e != i0 && logit[e] > v1) { v1 = logit[e]; i1 = e; }
        }
        // softmax over the two kept logits (others are -inf -> 0)
        const float e1  = expf(v1 - v0);
        const float inv = 1.f / (1.f + e1);
        top_idx[t]            = i0;
        top_idx[T_TOKENS + t] = i1;
        top_prob[t]            = inv;        // prob of slot-0 expert
        top_prob[T_TOKENS + t] = e1 * inv;   // prob of slot-1 expert
    }
}

// ---------------------------------------------------------------------------
// Kernel 2: per-expert prefix scan over the 8192 slot-major entries.
// Stage top_idx into LDS (coalesced), then one wave per expert does a
// ballot-based 64-wide scan over 128 chunks from LDS (low latency).
// Also builds the inverse slot->entry map for the batches kernel.
// ---------------------------------------------------------------------------
__global__ void scan_kernel(const int* __restrict__ top_idx,
                            int* __restrict__ rank,          // [2*T]
                            int* __restrict__ slot_token)    // [NSLOTS], pre-set to -1
{
    __shared__ int sidx[2 * T_TOKENS];   // 32 KB
    for (int i = threadIdx.x; i < 2 * T_TOKENS; i += blockDim.x)
        sidx[i] = top_idx[i];
    __syncthreads();

    const int e    = threadIdx.x >> 6;   // expert = wave id (8 waves)
    const int lane = threadIdx.x & 63;

    int base = 0;
    for (int chunk = 0; chunk < (2 * T_TOKENS) / 64; ++chunk) {
        const int i = chunk * 64 + lane;
        const bool match = (sidx[i] == e);
        const unsigned long long m = __ballot(match);
        if (match) {
            const int r = base + __popcll(m & ((1ull << lane) - 1ull));
            const bool keep = (r < CAP);
            rank[i] = keep ? r : -1;
            if (keep) slot_token[e * CAP + r] = i;
        }
        base += __popcll(m);
    }
}

// ---------------------------------------------------------------------------
// Kernel 3: write exp_weights and exp_mask — every byte exactly once.
// One block per token; each block writes 2 x 10240 floats with float4
// nontemporal stores, inserting the <=2 nonzeros via per-element selects.
// ---------------------------------------------------------------------------
__global__ void weights_kernel(const int*   __restrict__ top_idx,
                               const float* __restrict__ top_prob,
                               const int*   __restrict__ rank,
                               float* __restrict__ exp_weights,   // [T,8,CAP]
                               float* __restrict__ exp_mask)      // [T,8,CAP]
{
    const int t  = blockIdx.x;
    const int e0 = top_idx[t];
    const int e1 = top_idx[T_TOKENS + t];
    const int r0 = rank[t];
    const int r1 = rank[T_TOKENS + t];
    const float w0 = top_prob[t];
    const float w1 = top_prob[T_TOKENS + t];

    // flat positions within the token's [8*CAP] row; -1 if dropped
    const int p0 = (r0 >= 0) ? (e0 * CAP + r0) : -1;
    const int p1 = (r1 >= 0) ? (e1 * CAP + r1) : -1;
    // mask matches reference semantics: exp_mask_out = (exp_weights != 0)
    const float m0 = (w0 != 0.f) ? 1.f : 0.f;
    const float m1 = (w1 != 0.f) ? 1.f : 0.f;

    f32x4* wout = reinterpret_cast<f32x4*>(exp_weights + (size_t)t * NSLOTS);
    f32x4* mout = reinterpret_cast<f32x4*>(exp_mask    + (size_t)t * NSLOTS);

#pragma unroll
    for (int f = threadIdx.x; f < NSLOTS / 4; f += 256) {
        const int b = 4 * f;
        f32x4 wv, mv;
        wv.x = (b     == p0) ? w0 : (b     == p1) ? w1 : 0.f;
        wv.y = (b + 1 == p0) ? w0 : (b + 1 == p1) ? w1 : 0.f;
        wv.z = (b + 2 == p0) ? w0 : (b + 2 == p1) ? w1 : 0.f;
        wv.w = (b + 3 == p0) ? w0 : (b + 3 == p1) ? w1 : 0.f;
        mv.x = (b     == p0) ? m0 : (b     == p1) ? m1 : 0.f;
        mv.y = (b + 1 == p0) ? m0 : (b + 1 == p1) ? m1 : 0.f;
        mv.z = (b + 2 == p0) ? m0 : (b + 2 == p1) ? m1 : 0.f;
        mv.w = (b + 3 == p0) ? m0 : (b + 3 == p1) ? m1 : 0.f;
        __builtin_nontemporal_store(wv, wout + f);
        __builtin_nontemporal_store(mv, mout + f);
    }
}

// ---------------------------------------------------------------------------
// Kernel 4: write expert_batches — every byte exactly once.
// One block per (expert, cap) slot: copy x[t] if the slot is filled,
// zeros otherwise. x fits in L3 (33.5 MB) so the gather is mostly cache-hit.
// ---------------------------------------------------------------------------
__global__ void batches_kernel(const float* __restrict__ x,
                               const int*   __restrict__ slot_token,
                               float* __restrict__ expert_batches) // [8,CAP,D]
{
    const int slot = blockIdx.x;          // e*CAP + r
    const int i = slot_token[slot];
    f32x4* dst = reinterpret_cast<f32x4*>(expert_batches + (size_t)slot * D_DIM);

    if (i >= 0) {
        const int t = i & (T_TOKENS - 1);
        const f32x4* src = reinterpret_cast<const f32x4*>(x + (size_t)t * D_DIM);
#pragma unroll
        for (int c = threadIdx.x; c < D_DIM / 4; c += 256)
            __builtin_nontemporal_store(src[c], dst + c);
    } else {
        const f32x4 z = {0.f, 0.f, 0.f, 0.f};
#pragma unroll
        for (int c = threadIdx.x; c < D_DIM / 4; c += 256)
            __builtin_nontemporal_store(z, dst + c);
    }
}

// ---------------------------------------------------------------------------
extern "C" void kernel_launch(void* const* d_in, const int* in_sizes, int n_in,
                              void* d_out, int out_size, void* d_ws, size_t ws_size,
                              hipStream_t stream)
{
    const float* x       = (const float*)d_in[0];
    const float* noise   = (const float*)d_in[1];
    const float* w_g     = (const float*)d_in[2];
    const float* w_noise = (const float*)d_in[3];

    float* out = (float*)d_out;
    const size_t n_ew = (size_t)T_TOKENS * NEXP * CAP;   // 41,943,040
    float* exp_weights    = out;
    float* exp_mask       = out + n_ew;
    float* expert_batches = out + 2 * n_ew;

    int*   top_idx    = (int*)d_ws;                                      // 8192 ints
    float* top_prob   = (float*)((char*)d_ws + 2 * T_TOKENS * 4);        // 8192 floats
    int*   rank       = (int*)((char*)d_ws + 4 * T_TOKENS * 4);          // 8192 ints
    int*   slot_token = (int*)((char*)d_ws + 6 * T_TOKENS * 4);          // 10240 ints

    // slot_token := -1 (0xFF pattern). Tiny (40 KB).
    (void)hipMemsetAsync(slot_token, 0xFF, NSLOTS * sizeof(int), stream);

    gating_kernel<<<T_TOKENS / 4, 256, 0, stream>>>(x, noise, w_g, w_noise,
                                                    top_idx, top_prob);
    scan_kernel<<<1, 512, 0, stream>>>(top_idx, rank, slot_token);
    weights_kernel<<<T_TOKENS, 256, 0, stream>>>(top_idx, top_prob, rank,
                                                 exp_weights, exp_mask);
    batches_kernel<<<NSLOTS, 256, 0, stream>>>(x, slot_token, expert_batches);
}

// Round 4
// 121.170 us; speedup vs baseline: 1.3439x; 1.1652x over previous
//
#include <hip/hip_runtime.h>

// Problem constants (from reference)
#define T_TOKENS 4096      // B*C = 4*1024
#define D_DIM    2048
#define NEXP     8
#define CAP      1280      // floor(2 * 1.25 * 4096 / 8), already even
#define NSLOTS   (NEXP * CAP)   // 10240

// native 16-byte vector type (works with __builtin_nontemporal_store)
typedef float f32x4 __attribute__((ext_vector_type(4)));

// ---------------------------------------------------------------------------
// Kernel 1: gating. One wave (64 lanes) per token.
// 16 dot products (8 w_g + 8 w_noise) of length 2048; lane 0 applies
// softplus*noise, picks top-2 (JAX tie-break: lowest index first), computes
// the 2-way softmax, writes idx/prob in slot-major order.
// ---------------------------------------------------------------------------
__global__ void gating_kernel(const float* __restrict__ x,
                              const float* __restrict__ noise,
                              const float* __restrict__ w_g,
                              const float* __restrict__ w_noise,
                              int*   __restrict__ top_idx,    // [2*T] slot-major
                              float* __restrict__ top_prob)   // [2*T] slot-major
{
    const int wave = threadIdx.x >> 6;
    const int lane = threadIdx.x & 63;
    const int t = blockIdx.x * 4 + wave;
    if (t >= T_TOKENS) return;

    const f32x4* xv = reinterpret_cast<const f32x4*>(x + (size_t)t * D_DIM);

    float acc[16];
#pragma unroll
    for (int j = 0; j < 16; ++j) acc[j] = 0.f;

#pragma unroll
    for (int it = 0; it < 8; ++it) {
        const int c = it * 64 + lane;   // float4 column index
        const f32x4 xval = xv[c];
#pragma unroll
        for (int e = 0; e < NEXP; ++e) {
            const f32x4 g = reinterpret_cast<const f32x4*>(w_g + (size_t)e * D_DIM)[c];
            acc[e] += xval.x * g.x + xval.y * g.y + xval.z * g.z + xval.w * g.w;
            const f32x4 n = reinterpret_cast<const f32x4*>(w_noise + (size_t)e * D_DIM)[c];
            acc[8 + e] += xval.x * n.x + xval.y * n.y + xval.z * n.z + xval.w * n.w;
        }
    }

#pragma unroll
    for (int j = 0; j < 16; ++j) {
        float v = acc[j];
#pragma unroll
        for (int off = 32; off > 0; off >>= 1) v += __shfl_down(v, off, 64);
        acc[j] = v;   // valid on lane 0
    }

    if (lane == 0) {
        float logit[NEXP];
#pragma unroll
        for (int e = 0; e < NEXP; ++e) {
            const float z = acc[8 + e];
            const float sp = fmaxf(z, 0.f) + log1pf(expf(-fabsf(z)));  // stable softplus
            logit[e] = acc[e] + sp * noise[(size_t)t * NEXP + e];
        }
        int i0 = 0; float v0 = logit[0];
#pragma unroll
        for (int e = 1; e < NEXP; ++e) {
            if (logit[e] > v0) { v0 = logit[e]; i0 = e; }
        }
        int i1 = -1; float v1 = -3.402823466e38f;
#pragma unroll
        for (int e = 0; e < NEXP; ++e) {
            if (e != i0 && logit[e] > v1) { v1 = logit[e]; i1 = e; }
        }
        const float e1  = expf(v1 - v0);
        const float inv = 1.f / (1.f + e1);
        top_idx[t]            = i0;
        top_idx[T_TOKENS + t] = i1;
        top_prob[t]            = inv;
        top_prob[T_TOKENS + t] = e1 * inv;
    }
}

// ---------------------------------------------------------------------------
// Kernel 2: per-expert capacity scan. One block per expert (8 blocks, 512
// threads = 8 waves). Two-phase: per-wave counts -> exclusive prefix ->
// rank pass. Each block also inits its own slot_token range (no memset).
// Entry i (slot-major, i = s*T + t) belongs to exactly one expert, so every
// rank[i] is written by exactly one block.
// ---------------------------------------------------------------------------
__global__ void scan_kernel(const int* __restrict__ top_idx,
                            int* __restrict__ rank,          // [2*T]
                            int* __restrict__ slot_token)    // [NSLOTS]
{
    __shared__ int sidx[2 * T_TOKENS];   // 32 KB
    __shared__ int scnt[8];

    const int e    = blockIdx.x;         // expert
    const int w    = threadIdx.x >> 6;   // wave id (0..7)
    const int lane = threadIdx.x & 63;

    // stage indices (coalesced) + init this expert's slot_token range to -1
    for (int i = threadIdx.x; i < 2 * T_TOKENS; i += 512)
        sidx[i] = top_idx[i];
    for (int r = threadIdx.x; r < CAP; r += 512)
        slot_token[e * CAP + r] = -1;
    __syncthreads();

    // phase A: wave w counts matches in its contiguous 16-chunk range
    int cnt = 0;
#pragma unroll
    for (int c = 0; c < 16; ++c) {
        const int i = (w * 16 + c) * 64 + lane;
        cnt += __popcll(__ballot(sidx[i] == e));
    }
    if (lane == 0) scnt[w] = cnt;   // same value in every lane; popcount of full ballot
    __syncthreads();

    // exclusive prefix over the 8 wave counts
    int base = 0;
#pragma unroll
    for (int j = 0; j < 8; ++j) if (j < w) base += scnt[j];

    // phase B: assign ranks
#pragma unroll
    for (int c = 0; c < 16; ++c) {
        const int i = (w * 16 + c) * 64 + lane;
        const bool match = (sidx[i] == e);
        const unsigned long long m = __ballot(match);
        if (match) {
            const int r = base + __popcll(m & ((1ull << lane) - 1ull));
            const bool keep = (r < CAP);
            rank[i] = keep ? r : -1;
            if (keep) slot_token[e * CAP + r] = i;
        }
        base += __popcll(m);
    }
}

// ---------------------------------------------------------------------------
// Kernel 3 (fused writer): every output byte written exactly once.
//  blocks [0, T)            : exp_weights + exp_mask row for token bid
//  blocks [T, T + NSLOTS)   : expert_batches row for slot bid - T
// ---------------------------------------------------------------------------
__global__ void writer_kernel(const float* __restrict__ x,
                              const int*   __restrict__ top_idx,
                              const float* __restrict__ top_prob,
                              const int*   __restrict__ rank,
                              const int*   __restrict__ slot_token,
                              float* __restrict__ exp_weights,    // [T,8,CAP]
                              float* __restrict__ exp_mask,       // [T,8,CAP]
                              float* __restrict__ expert_batches) // [8,CAP,D]
{
    const int bid = blockIdx.x;

    if (bid < T_TOKENS) {
        // ---- weights/mask row ----
        const int t  = bid;
        const int e0 = top_idx[t];
        const int e1 = top_idx[T_TOKENS + t];
        const int r0 = rank[t];
        const int r1 = rank[T_TOKENS + t];
        const float w0 = top_prob[t];
        const float w1 = top_prob[T_TOKENS + t];

        const int p0 = (r0 >= 0) ? (e0 * CAP + r0) : -1;
        const int p1 = (r1 >= 0) ? (e1 * CAP + r1) : -1;
        const float m0 = (w0 != 0.f) ? 1.f : 0.f;
        const float m1 = (w1 != 0.f) ? 1.f : 0.f;

        f32x4* wout = reinterpret_cast<f32x4*>(exp_weights + (size_t)t * NSLOTS);
        f32x4* mout = reinterpret_cast<f32x4*>(exp_mask    + (size_t)t * NSLOTS);

#pragma unroll
        for (int f = threadIdx.x; f < NSLOTS / 4; f += 256) {
            const int b = 4 * f;
            f32x4 wv, mv;
            wv.x = (b     == p0) ? w0 : (b     == p1) ? w1 : 0.f;
            wv.y = (b + 1 == p0) ? w0 : (b + 1 == p1) ? w1 : 0.f;
            wv.z = (b + 2 == p0) ? w0 : (b + 2 == p1) ? w1 : 0.f;
            wv.w = (b + 3 == p0) ? w0 : (b + 3 == p1) ? w1 : 0.f;
            mv.x = (b     == p0) ? m0 : (b     == p1) ? m1 : 0.f;
            mv.y = (b + 1 == p0) ? m0 : (b + 1 == p1) ? m1 : 0.f;
            mv.z = (b + 2 == p0) ? m0 : (b + 2 == p1) ? m1 : 0.f;
            mv.w = (b + 3 == p0) ? m0 : (b + 3 == p1) ? m1 : 0.f;
            __builtin_nontemporal_store(wv, wout + f);
            __builtin_nontemporal_store(mv, mout + f);
        }
    } else {
        // ---- expert_batches row ----
        const int slot = bid - T_TOKENS;      // e*CAP + r
        const int i = slot_token[slot];
        f32x4* dst = reinterpret_cast<f32x4*>(expert_batches + (size_t)slot * D_DIM);

        if (i >= 0) {
            const int t = i & (T_TOKENS - 1);
            const f32x4* src = reinterpret_cast<const f32x4*>(x + (size_t)t * D_DIM);
#pragma unroll
            for (int c = threadIdx.x; c < D_DIM / 4; c += 256)
                __builtin_nontemporal_store(src[c], dst + c);
        } else {
            const f32x4 z = {0.f, 0.f, 0.f, 0.f};
#pragma unroll
            for (int c = threadIdx.x; c < D_DIM / 4; c += 256)
                __builtin_nontemporal_store(z, dst + c);
        }
    }
}

// ---------------------------------------------------------------------------
extern "C" void kernel_launch(void* const* d_in, const int* in_sizes, int n_in,
                              void* d_out, int out_size, void* d_ws, size_t ws_size,
                              hipStream_t stream)
{
    const float* x       = (const float*)d_in[0];
    const float* noise   = (const float*)d_in[1];
    const float* w_g     = (const float*)d_in[2];
    const float* w_noise = (const float*)d_in[3];

    float* out = (float*)d_out;
    const size_t n_ew = (size_t)T_TOKENS * NEXP * CAP;   // 41,943,040
    float* exp_weights    = out;
    float* exp_mask       = out + n_ew;
    float* expert_batches = out + 2 * n_ew;

    int*   top_idx    = (int*)d_ws;                                      // 8192 ints
    float* top_prob   = (float*)((char*)d_ws + 2 * T_TOKENS * 4);        // 8192 floats
    int*   rank       = (int*)((char*)d_ws + 4 * T_TOKENS * 4);          // 8192 ints
    int*   slot_token = (int*)((char*)d_ws + 6 * T_TOKENS * 4);          // 10240 ints

    gating_kernel<<<T_TOKENS / 4, 256, 0, stream>>>(x, noise, w_g, w_noise,
                                                    top_idx, top_prob);
    scan_kernel<<<NEXP, 512, 0, stream>>>(top_idx, rank, slot_token);
    writer_kernel<<<T_TOKENS + NSLOTS, 256, 0, stream>>>(x, top_idx, top_prob,
                                                         rank, slot_token,
                                                         exp_weights, exp_mask,
                                                         expert_batches);
}

// Round 5
// 118.988 us; speedup vs baseline: 1.3685x; 1.0183x over previous
//
#include <hip/hip_runtime.h>

// Problem constants (from reference)
#define T_TOKENS 4096      // B*C = 4*1024
#define D_DIM    2048
#define NEXP     8
#define CAP      1280      // floor(2 * 1.25 * 4096 / 8), already even
#define NSLOTS   (NEXP * CAP)   // 10240

#define GATE_BLOCKS (T_TOKENS / 4)          // 1024
#define FILL_FLOATS (2ull * T_TOKENS * NSLOTS)   // exp_weights + exp_mask = 83,886,080
#define FILL_VEC_PER_BLOCK 4096             // f32x4 per fill block (64 KB)
#define FILL_BLOCKS (FILL_FLOATS / (4 * FILL_VEC_PER_BLOCK))   // 5120

// native 16-byte vector type (works with __builtin_nontemporal_store)
typedef float f32x4 __attribute__((ext_vector_type(4)));

// ---------------------------------------------------------------------------
// Kernel 1 (fused): blocks [0, GATE_BLOCKS) run gating (4 tokens each, one
// wave per token); remaining FILL_BLOCKS zero-fill exp_weights + exp_mask.
// Gating blocks come first so they start executing immediately; the fill
// saturates write BW while gating's L2-bound dot products hide under it.
// ---------------------------------------------------------------------------
__global__ void gate_fill_kernel(const float* __restrict__ x,
                                 const float* __restrict__ noise,
                                 const float* __restrict__ w_g,
                                 const float* __restrict__ w_noise,
                                 int*   __restrict__ top_idx,    // [2*T] slot-major
                                 float* __restrict__ top_prob,   // [2*T] slot-major
                                 float* __restrict__ wm_base)    // exp_weights (mask follows)
{
    if (blockIdx.x >= GATE_BLOCKS) {
        // ---- zero-fill portion ----
        const size_t blk = blockIdx.x - GATE_BLOCKS;
        f32x4* dst = reinterpret_cast<f32x4*>(wm_base) + blk * FILL_VEC_PER_BLOCK;
#pragma unroll
        for (int j = 0; j < FILL_VEC_PER_BLOCK / 256; ++j) {
            const f32x4 z = {0.f, 0.f, 0.f, 0.f};
            __builtin_nontemporal_store(z, dst + j * 256 + threadIdx.x);
        }
        return;
    }

    // ---- gating portion ----
    const int wave = threadIdx.x >> 6;
    const int lane = threadIdx.x & 63;
    const int t = blockIdx.x * 4 + wave;

    const f32x4* xv = reinterpret_cast<const f32x4*>(x + (size_t)t * D_DIM);

    float acc[16];
#pragma unroll
    for (int j = 0; j < 16; ++j) acc[j] = 0.f;

#pragma unroll
    for (int it = 0; it < 8; ++it) {
        const int c = it * 64 + lane;   // float4 column index
        const f32x4 xval = xv[c];
#pragma unroll
        for (int e = 0; e < NEXP; ++e) {
            const f32x4 g = reinterpret_cast<const f32x4*>(w_g + (size_t)e * D_DIM)[c];
            acc[e] += xval.x * g.x + xval.y * g.y + xval.z * g.z + xval.w * g.w;
            const f32x4 n = reinterpret_cast<const f32x4*>(w_noise + (size_t)e * D_DIM)[c];
            acc[8 + e] += xval.x * n.x + xval.y * n.y + xval.z * n.z + xval.w * n.w;
        }
    }

#pragma unroll
    for (int j = 0; j < 16; ++j) {
        float v = acc[j];
#pragma unroll
        for (int off = 32; off > 0; off >>= 1) v += __shfl_down(v, off, 64);
        acc[j] = v;   // valid on lane 0
    }

    if (lane == 0) {
        float logit[NEXP];
#pragma unroll
        for (int e = 0; e < NEXP; ++e) {
            const float z = acc[8 + e];
            const float sp = fmaxf(z, 0.f) + log1pf(expf(-fabsf(z)));  // stable softplus
            logit[e] = acc[e] + sp * noise[(size_t)t * NEXP + e];
        }
        int i0 = 0; float v0 = logit[0];
#pragma unroll
        for (int e = 1; e < NEXP; ++e) {
            if (logit[e] > v0) { v0 = logit[e]; i0 = e; }
        }
        int i1 = -1; float v1 = -3.402823466e38f;
#pragma unroll
        for (int e = 0; e < NEXP; ++e) {
            if (e != i0 && logit[e] > v1) { v1 = logit[e]; i1 = e; }
        }
        const float e1  = expf(v1 - v0);
        const float inv = 1.f / (1.f + e1);
        top_idx[t]            = i0;
        top_idx[T_TOKENS + t] = i1;
        top_prob[t]            = inv;
        top_prob[T_TOKENS + t] = e1 * inv;
    }
}

// ---------------------------------------------------------------------------
// Kernel 2: per-expert capacity scan + sparse scatter. One block per expert
// (8 blocks, 512 threads = 8 waves). Two-phase: per-wave counts -> exclusive
// prefix -> rank pass that directly scatters the (weight, mask) scalars onto
// the zeroed buffers and builds slot_token (its own range inited, no memset).
// ---------------------------------------------------------------------------
__global__ void scan_scatter_kernel(const int*   __restrict__ top_idx,
                                    const float* __restrict__ top_prob,
                                    int*   __restrict__ slot_token,     // [NSLOTS]
                                    float* __restrict__ exp_weights,    // [T,8,CAP]
                                    float* __restrict__ exp_mask)       // [T,8,CAP]
{
    __shared__ int sidx[2 * T_TOKENS];   // 32 KB
    __shared__ int scnt[8];

    const int e    = blockIdx.x;         // expert
    const int w    = threadIdx.x >> 6;   // wave id (0..7)
    const int lane = threadIdx.x & 63;

    for (int i = threadIdx.x; i < 2 * T_TOKENS; i += 512)
        sidx[i] = top_idx[i];
    for (int r = threadIdx.x; r < CAP; r += 512)
        slot_token[e * CAP + r] = -1;
    __syncthreads();

    // phase A: wave w counts matches in its contiguous 16-chunk range
    int cnt = 0;
#pragma unroll
    for (int c = 0; c < 16; ++c) {
        const int i = (w * 16 + c) * 64 + lane;
        cnt += __popcll(__ballot(sidx[i] == e));
    }
    if (lane == 0) scnt[w] = cnt;
    __syncthreads();

    int base = 0;
#pragma unroll
    for (int j = 0; j < 8; ++j) if (j < w) base += scnt[j];

    // phase B: assign ranks, scatter scalars, build slot map
#pragma unroll
    for (int c = 0; c < 16; ++c) {
        const int i = (w * 16 + c) * 64 + lane;
        const bool match = (sidx[i] == e);
        const unsigned long long m = __ballot(match);
        if (match) {
            const int r = base + __popcll(m & ((1ull << lane) - 1ull));
            if (r < CAP) {
                slot_token[e * CAP + r] = i;
                const int t = i & (T_TOKENS - 1);
                const float wgt = top_prob[i];
                const size_t off = (size_t)t * NSLOTS + e * CAP + r;
                exp_weights[off] = wgt;
                exp_mask[off]    = (wgt != 0.f) ? 1.f : 0.f;
            }
        }
        base += __popcll(m);
    }
}

// ---------------------------------------------------------------------------
// Kernel 3: expert_batches — every byte written exactly once.
// One block per (expert, cap) slot: copy x[t] if filled, zeros otherwise.
// x (33.5 MB) is L3-resident after K1, so the gather is mostly cache-hit.
// ---------------------------------------------------------------------------
__global__ void batches_kernel(const float* __restrict__ x,
                               const int*   __restrict__ slot_token,
                               float* __restrict__ expert_batches) // [8,CAP,D]
{
    const int slot = blockIdx.x;          // e*CAP + r
    const int i = slot_token[slot];
    f32x4* dst = reinterpret_cast<f32x4*>(expert_batches + (size_t)slot * D_DIM);

    if (i >= 0) {
        const int t = i & (T_TOKENS - 1);
        const f32x4* src = reinterpret_cast<const f32x4*>(x + (size_t)t * D_DIM);
#pragma unroll
        for (int c = threadIdx.x; c < D_DIM / 4; c += 256)
            __builtin_nontemporal_store(src[c], dst + c);
    } else {
        const f32x4 z = {0.f, 0.f, 0.f, 0.f};
#pragma unroll
        for (int c = threadIdx.x; c < D_DIM / 4; c += 256)
            __builtin_nontemporal_store(z, dst + c);
    }
}

// ---------------------------------------------------------------------------
extern "C" void kernel_launch(void* const* d_in, const int* in_sizes, int n_in,
                              void* d_out, int out_size, void* d_ws, size_t ws_size,
                              hipStream_t stream)
{
    const float* x       = (const float*)d_in[0];
    const float* noise   = (const float*)d_in[1];
    const float* w_g     = (const float*)d_in[2];
    const float* w_noise = (const float*)d_in[3];

    float* out = (float*)d_out;
    const size_t n_ew = (size_t)T_TOKENS * NEXP * CAP;   // 41,943,040
    float* exp_weights    = out;
    float* exp_mask       = out + n_ew;
    float* expert_batches = out + 2 * n_ew;

    int*   top_idx    = (int*)d_ws;                                      // 8192 ints
    float* top_prob   = (float*)((char*)d_ws + 2 * T_TOKENS * 4);        // 8192 floats
    int*   slot_token = (int*)((char*)d_ws + 4 * T_TOKENS * 4);          // 10240 ints

    gate_fill_kernel<<<GATE_BLOCKS + FILL_BLOCKS, 256, 0, stream>>>(
        x, noise, w_g, w_noise, top_idx, top_prob, exp_weights);
    scan_scatter_kernel<<<NEXP, 512, 0, stream>>>(top_idx, top_prob, slot_token,
                                                  exp_weights, exp_mask);
    batches_kernel<<<NSLOTS, 256, 0, stream>>>(x, slot_token, expert_batches);
}